// Round 2
// baseline (921.049 us; speedup 1.0000x reference)
//
#include <hip/hip_runtime.h>
#include <hip/hip_bf16.h>

// ---------------- problem constants ----------------
#define T_TOKENS 8192
#define HD 1024
#define FF 4096
#define NEXP 8
#define NR_MAX 18432   // 16384 picks + 8 experts * 256-row padding

typedef __attribute__((ext_vector_type(8))) short bf16x8;
typedef __attribute__((ext_vector_type(4))) float f32x4;

static __device__ __forceinline__ float b2f(ushort u) {
    union { unsigned u; float f; } c; c.u = ((unsigned)u) << 16; return c.f;
}
static __device__ __forceinline__ ushort f2b(float f) {
    union { float f; unsigned u; } c; c.f = f;
    unsigned r = c.u + 0x7fffu + ((c.u >> 16) & 1u);   // RNE
    return (ushort)(r >> 16);
}

// ---------------- gate: logits, softmax, top-2, counts ----------------
__global__ __launch_bounds__(256) void gate_kernel(
    const float* __restrict__ x, const float* __restrict__ Wg, const float* __restrict__ bg,
    float* __restrict__ logits, int* __restrict__ counts,
    int* __restrict__ e0a, int* __restrict__ e1a,
    float* __restrict__ w0a, float* __restrict__ w1a)
{
    int t = blockIdx.x * 4 + (threadIdx.x >> 6);
    int l = threadIdx.x & 63;
    const float* xr = x + (size_t)t * HD;
    float acc[8] = {0,0,0,0,0,0,0,0};
    #pragma unroll
    for (int i = 0; i < 4; ++i) {
        int h0 = i * 256 + l * 4;
        float4 xv = *(const float4*)(xr + h0);
        #pragma unroll
        for (int j = 0; j < 4; ++j) {
            float xs = (&xv.x)[j];
            const float4* wr = (const float4*)(Wg + (size_t)(h0 + j) * NEXP);
            float4 wa = wr[0], wb = wr[1];
            acc[0] = fmaf(xs, wa.x, acc[0]);
            acc[1] = fmaf(xs, wa.y, acc[1]);
            acc[2] = fmaf(xs, wa.z, acc[2]);
            acc[3] = fmaf(xs, wa.w, acc[3]);
            acc[4] = fmaf(xs, wb.x, acc[4]);
            acc[5] = fmaf(xs, wb.y, acc[5]);
            acc[6] = fmaf(xs, wb.z, acc[6]);
            acc[7] = fmaf(xs, wb.w, acc[7]);
        }
    }
    #pragma unroll
    for (int off = 32; off > 0; off >>= 1) {
        #pragma unroll
        for (int e = 0; e < 8; ++e) acc[e] += __shfl_down(acc[e], off, 64);
    }
    if (l == 0) {
        float lg[8];
        #pragma unroll
        for (int e = 0; e < 8; ++e) {
            lg[e] = acc[e] + bg[e];
            logits[(size_t)t * NEXP + e] = lg[e];
        }
        float m = lg[0];
        #pragma unroll
        for (int e = 1; e < 8; ++e) m = fmaxf(m, lg[e]);
        float p[8], s = 0.f;
        #pragma unroll
        for (int e = 0; e < 8; ++e) { p[e] = expf(lg[e] - m); s += p[e]; }
        float inv = 1.f / s;
        #pragma unroll
        for (int e = 0; e < 8; ++e) p[e] *= inv;
        int i0 = 0;
        #pragma unroll
        for (int e = 1; e < 8; ++e) if (p[e] > p[i0]) i0 = e;
        int i1 = (i0 == 0) ? 1 : 0;
        #pragma unroll
        for (int e = 0; e < 8; ++e) if (e != i0 && p[e] > p[i1]) i1 = e;
        float ed = expf(p[i1] - p[i0]);          // <= 1
        float w0 = 1.f / (1.f + ed);
        float w1 = ed / (1.f + ed);
        e0a[t] = i0; e1a[t] = i1; w0a[t] = w0; w1a[t] = w1;
        atomicAdd(&counts[i0], 1);
        atomicAdd(&counts[i1], 1);
    }
}

// ---------------- offsets: pad each expert segment to 256 rows ----------------
__global__ void offsets_kernel(const int* __restrict__ counts, int* __restrict__ off) {
    if (threadIdx.x == 0) {
        int o = 0;
        for (int e = 0; e < 8; ++e) { off[e] = o; o += (counts[e] + 255) & ~255; }
        off[8] = o;
    }
}

// ---------------- assign rows ----------------
__global__ __launch_bounds__(256) void assign_kernel(
    const int* __restrict__ e0a, const int* __restrict__ e1a,
    const int* __restrict__ off, int* __restrict__ fill,
    int* __restrict__ row0, int* __restrict__ row1, int* __restrict__ row_token)
{
    int t = blockIdx.x * 256 + threadIdx.x;
    if (t >= T_TOKENS) return;
    int e0 = e0a[t];
    int r0 = off[e0] + atomicAdd(&fill[e0], 1);
    row0[t] = r0; row_token[r0] = t;
    int e1 = e1a[t];
    int r1 = off[e1] + atomicAdd(&fill[e1], 1);
    row1[t] = r1; row_token[r1] = t;
}

// ---------------- gather x rows -> bf16 X_perm (zeros in padding rows) ----------------
__global__ __launch_bounds__(256) void gather_kernel(
    const float* __restrict__ x, const int* __restrict__ row_token, ushort* __restrict__ Xp)
{
    int r = blockIdx.x;
    int tok = row_token[r];
    int c = threadIdx.x * 4;
    ushort4 o;
    if (tok >= 0 && tok < T_TOKENS) {
        float4 v = *(const float4*)(x + (size_t)tok * HD + c);
        o.x = f2b(v.x); o.y = f2b(v.y); o.z = f2b(v.z); o.w = f2b(v.w);
    } else {
        o.x = 0; o.y = 0; o.z = 0; o.w = 0;
    }
    *(ushort4*)(Xp + (size_t)r * HD + c) = o;
}

// ---------------- fp32 [R][C] -> bf16 [C][R] transpose+convert (per expert in z) ----------------
__global__ __launch_bounds__(256) void transpose_cvt_kernel(
    const float* __restrict__ in, ushort* __restrict__ out, int R, int C)
{
    __shared__ ushort tile[64][65];
    size_t esz = (size_t)R * C;
    const float* ein = in + (size_t)blockIdx.z * esz;
    ushort* eout = out + (size_t)blockIdx.z * esz;
    int c0 = blockIdx.x * 64, r0 = blockIdx.y * 64;
    int tr = threadIdx.x >> 4;            // 0..15
    int tc = (threadIdx.x & 15) * 4;      // 0..60
    #pragma unroll
    for (int i = 0; i < 4; ++i) {
        int r = tr + i * 16;
        float4 v = *(const float4*)(ein + (size_t)(r0 + r) * C + c0 + tc);
        tile[r][tc + 0] = f2b(v.x);
        tile[r][tc + 1] = f2b(v.y);
        tile[r][tc + 2] = f2b(v.z);
        tile[r][tc + 3] = f2b(v.w);
    }
    __syncthreads();
    #pragma unroll
    for (int i = 0; i < 4; ++i) {
        int cc = tr + i * 16;             // input col == output row
        ushort4 o;
        o.x = tile[tc + 0][cc];
        o.y = tile[tc + 1][cc];
        o.z = tile[tc + 2][cc];
        o.w = tile[tc + 3][cc];
        *(ushort4*)(eout + (size_t)(c0 + cc) * R + r0 + tc) = o;
    }
}

// ---------------- MFMA GEMM, counted-vmcnt multi-phase (T1+T2+T3+T4+T5) ----------------
// C[rows x NTOT] = A[rows x K] * B^T[NTOT x K] + bias, 256xBN tile, BK=32,
// 8 waves (WM x WN), ring-4 LDS, prefetch t+3, one counted vmcnt per K-tile.
template<int K, int NTOT, bool RELU, int BN, int WM, int WN>
__global__ __launch_bounds__(512, 2) void gemm8p_kernel(
    const ushort* __restrict__ A, const ushort* __restrict__ Bt,
    const float* __restrict__ bias, ushort* __restrict__ Out,
    const int* __restrict__ off)
{
    constexpr int BM = 256, BK = 32;
    constexpr int MREP = BM / (WM * 16);          // 8 (G1) / 4 (G2)
    constexpr int NREP = BN / (WN * 16);          // 4
    constexpr int PHASES = (MREP * NREP) / 16;    // 2 (G1) / 1 (G2)
    constexpr int MPP = MREP / PHASES;            // 4
    constexpr int A_ISS = (BM * BK) / (512 * 8);  // 2
    constexpr int B_ISS = (BN * BK) / (512 * 8);  // 2 (G1) / 1 (G2)
    constexpr int LPT = A_ISS + B_ISS;            // loads per K-tile per thread
    constexpr int KT = K / BK;
    constexpr int NT = NTOT / BN;

    __shared__ __align__(16) ushort ldsA[4][BM * BK];
    __shared__ __align__(16) ushort ldsB[4][BN * BK];

    // bijective XCD swizzle (gridDim.x is a multiple of 8)
    int nwg = gridDim.x;
    int bid = blockIdx.x;
    int wgid = (bid & 7) * (nwg >> 3) + (bid >> 3);
    int ntile = wgid % NT;
    int mtile = wgid / NT;
    int r0 = mtile * BM;
    int total = off[8];
    if (r0 >= total) return;
    int e = 0;
    #pragma unroll
    for (int q = 0; q < 7; ++q) if (r0 >= off[q + 1]) e = q + 1;

    int tid = threadIdx.x;
    int wid = tid >> 6, lane = tid & 63;
    int wr = wid / WN, wc = wid % WN;
    int lr = lane & 15, lk = lane >> 4;

    const ushort* Ab = A + (size_t)r0 * K;
    const ushort* Bb = Bt + ((size_t)e * NTOT + (size_t)ntile * BN) * K;

    int srow = tid >> 2;                       // 0..127
    int schunk = (tid & 3) ^ (srow & 3);       // pre-swizzled global source chunk

    auto stageA = [&](int kt) {
        ushort* dst = &ldsA[kt & 3][tid * 8];
        const ushort* g = Ab + (size_t)kt * BK + (size_t)srow * K + schunk * 8;
        #pragma unroll
        for (int i = 0; i < A_ISS; ++i)
            __builtin_amdgcn_global_load_lds(
                (const __attribute__((address_space(1))) void*)(g + (size_t)i * 128 * K),
                (__attribute__((address_space(3))) void*)(dst + i * 4096),
                16, 0, 0);
    };
    auto stageB = [&](int kt) {
        ushort* dst = &ldsB[kt & 3][tid * 8];
        const ushort* g = Bb + (size_t)kt * BK + (size_t)srow * K + schunk * 8;
        #pragma unroll
        for (int i = 0; i < B_ISS; ++i)
            __builtin_amdgcn_global_load_lds(
                (const __attribute__((address_space(1))) void*)(g + (size_t)i * 128 * K),
                (__attribute__((address_space(3))) void*)(dst + i * 4096),
                16, 0, 0);
    };
    auto ldA = [&](int slot, int m) -> bf16x8 {
        int row = wr * (BM / WM) + m * 16 + lr;
        int chunk = lk ^ (row & 3);
        return *(const bf16x8*)&ldsA[slot][row * 32 + chunk * 8];
    };
    auto ldB = [&](int slot, int n) -> bf16x8 {
        int row = wc * (BN / WN) + n * 16 + lr;
        int chunk = lk ^ (row & 3);
        return *(const bf16x8*)&ldsB[slot][row * 32 + chunk * 8];
    };

    f32x4 acc[MREP][NREP];
    #pragma unroll
    for (int m = 0; m < MREP; ++m)
        #pragma unroll
        for (int n = 0; n < NREP; ++n) acc[m][n] = (f32x4){0.f, 0.f, 0.f, 0.f};

    // prologue: stage K-tiles 0,1,2; wait for tile 0 (counted)
    stageA(0); stageB(0);
    stageA(1); stageB(1);
    stageA(2); stageB(2);
    asm volatile("s_waitcnt vmcnt(%0)" :: "n"(2 * LPT) : "memory");
    __builtin_amdgcn_sched_barrier(0);
    __builtin_amdgcn_s_barrier();
    __builtin_amdgcn_sched_barrier(0);

    for (int kt = 0; kt < KT; ++kt) {
        int slot = kt & 3;
        // ---- phase 0: frags + A-prefetch(t+3) ----
        bf16x8 a0[MPP], b[NREP];
        #pragma unroll
        for (int m = 0; m < MPP; ++m) a0[m] = ldA(slot, m);
        #pragma unroll
        for (int n = 0; n < NREP; ++n) b[n] = ldB(slot, n);
        if (kt + 3 < KT) { stageA(kt + 3); if (PHASES == 1) stageB(kt + 3); }
        __builtin_amdgcn_sched_barrier(0);
        __builtin_amdgcn_s_barrier();
        asm volatile("s_waitcnt lgkmcnt(0)" ::: "memory");
        __builtin_amdgcn_sched_barrier(0);
        __builtin_amdgcn_s_setprio(1);
        __builtin_amdgcn_sched_barrier(0);
        #pragma unroll
        for (int m = 0; m < MPP; ++m)
            #pragma unroll
            for (int n = 0; n < NREP; ++n)
                acc[m][n] = __builtin_amdgcn_mfma_f32_16x16x32_bf16(a0[m], b[n], acc[m][n], 0, 0, 0);
        __builtin_amdgcn_sched_barrier(0);
        __builtin_amdgcn_s_setprio(0);
        __builtin_amdgcn_sched_barrier(0);

        if constexpr (PHASES == 2) {
            // ---- phase 1: other m-half + B-prefetch(t+3), reuse b[] ----
            __builtin_amdgcn_s_barrier();
            bf16x8 a1[MPP];
            #pragma unroll
            for (int m = 0; m < MPP; ++m) a1[m] = ldA(slot, MPP + m);
            if (kt + 3 < KT) stageB(kt + 3);
            __builtin_amdgcn_sched_barrier(0);
            __builtin_amdgcn_s_barrier();
            asm volatile("s_waitcnt lgkmcnt(0)" ::: "memory");
            __builtin_amdgcn_sched_barrier(0);
            __builtin_amdgcn_s_setprio(1);
            __builtin_amdgcn_sched_barrier(0);
            #pragma unroll
            for (int m = 0; m < MPP; ++m)
                #pragma unroll
                for (int n = 0; n < NREP; ++n)
                    acc[MPP + m][n] = __builtin_amdgcn_mfma_f32_16x16x32_bf16(a1[m], b[n], acc[MPP + m][n], 0, 0, 0);
            __builtin_amdgcn_sched_barrier(0);
            __builtin_amdgcn_s_setprio(0);
            __builtin_amdgcn_sched_barrier(0);
        }

        // ---- end of K-tile: counted vmcnt (never 0 in steady state) ----
        if (kt + 4 <= KT)      { asm volatile("s_waitcnt vmcnt(%0)" :: "n"(2 * LPT) : "memory"); }
        else if (kt + 3 <= KT) { asm volatile("s_waitcnt vmcnt(%0)" :: "n"(LPT) : "memory"); }
        else                   { asm volatile("s_waitcnt vmcnt(0)" ::: "memory"); }
        __builtin_amdgcn_sched_barrier(0);
        __builtin_amdgcn_s_barrier();
        __builtin_amdgcn_sched_barrier(0);
    }

    // epilogue: bias (+ReLU) -> bf16. C/D map: col = lane&15, row = (lane>>4)*4 + j
    int c0 = ntile * BN + wc * (BN / WN);
    int rbase = r0 + wr * (BM / WM);
    #pragma unroll
    for (int ni = 0; ni < NREP; ++ni) {
        int n = c0 + ni * 16 + lr;
        float bv = bias[(size_t)e * NTOT + n];
        #pragma unroll
        for (int mi = 0; mi < MREP; ++mi) {
            int m = rbase + mi * 16 + lk * 4;
            #pragma unroll
            for (int j = 0; j < 4; ++j) {
                float v = acc[mi][ni][j] + bv;
                if (RELU) v = fmaxf(v, 0.f);
                Out[(size_t)(m + j) * NTOT + n] = f2b(v);
            }
        }
    }
}

// ---------------- combine: out[t] = w0*Y[r0] + w1*Y[r1] ----------------
__global__ __launch_bounds__(256) void combine_kernel(
    const ushort* __restrict__ Y, const int* __restrict__ row0, const int* __restrict__ row1,
    const float* __restrict__ w0a, const float* __restrict__ w1a, float* __restrict__ out)
{
    int t = blockIdx.x;
    int c = threadIdx.x * 4;
    int r0 = row0[t], r1 = row1[t];
    float w0 = w0a[t], w1 = w1a[t];
    ushort4 ya = *(const ushort4*)(Y + (size_t)r0 * HD + c);
    ushort4 yb = *(const ushort4*)(Y + (size_t)r1 * HD + c);
    float4 o;
    o.x = w0 * b2f(ya.x) + w1 * b2f(yb.x);
    o.y = w0 * b2f(ya.y) + w1 * b2f(yb.y);
    o.z = w0 * b2f(ya.z) + w1 * b2f(yb.z);
    o.w = w0 * b2f(ya.w) + w1 * b2f(yb.w);
    *(float4*)(out + (size_t)t * HD + c) = o;
}

// ---------------- workspace layout ----------------
#define WSA(x) (((x) + 255) & ~(size_t)255)
static constexpr size_t OFF_COUNTS = 0;
static constexpr size_t OFF_FILL   = 64;
static constexpr size_t OFF_OFF    = 128;
static constexpr size_t OFF_E0     = 256;
static constexpr size_t OFF_E1     = OFF_E0 + (size_t)T_TOKENS * 4;
static constexpr size_t OFF_W0     = OFF_E1 + (size_t)T_TOKENS * 4;
static constexpr size_t OFF_W1A    = OFF_W0 + (size_t)T_TOKENS * 4;
static constexpr size_t OFF_R0     = OFF_W1A + (size_t)T_TOKENS * 4;
static constexpr size_t OFF_R1     = OFF_R0 + (size_t)T_TOKENS * 4;
static constexpr size_t OFF_RT     = OFF_R1 + (size_t)T_TOKENS * 4;
static constexpr size_t OFF_XP     = WSA(OFF_RT + (size_t)NR_MAX * 4);
static constexpr size_t OFF_W1T    = OFF_XP  + (size_t)NR_MAX * HD * 2;
static constexpr size_t OFF_W2T    = OFF_W1T + (size_t)NEXP * FF * HD * 2;
static constexpr size_t OFF_H1     = OFF_W2T + (size_t)NEXP * HD * FF * 2;
static constexpr size_t OFF_Y      = OFF_H1  + (size_t)NR_MAX * FF * 2;
static constexpr size_t WS_NEEDED  = OFF_Y   + (size_t)NR_MAX * HD * 2;

extern "C" void kernel_launch(void* const* d_in, const int* in_sizes, int n_in,
                              void* d_out, int out_size, void* d_ws, size_t ws_size,
                              hipStream_t stream) {
    (void)in_sizes; (void)n_in; (void)out_size;
    const float* x  = (const float*)d_in[0];
    const float* Wg = (const float*)d_in[1];
    const float* bg = (const float*)d_in[2];
    const float* W1 = (const float*)d_in[3];
    const float* b1 = (const float*)d_in[4];
    const float* W2 = (const float*)d_in[5];
    const float* b2 = (const float*)d_in[6];
    float* out    = (float*)d_out;
    float* logits = out + (size_t)T_TOKENS * HD;

    if (ws_size < WS_NEEDED) return;  // need ~361 MB scratch

    char* ws = (char*)d_ws;
    int*    counts = (int*)(ws + OFF_COUNTS);
    int*    fill   = (int*)(ws + OFF_FILL);
    int*    offp   = (int*)(ws + OFF_OFF);
    int*    e0a    = (int*)(ws + OFF_E0);
    int*    e1a    = (int*)(ws + OFF_E1);
    float*  w0a    = (float*)(ws + OFF_W0);
    float*  w1a    = (float*)(ws + OFF_W1A);
    int*    row0   = (int*)(ws + OFF_R0);
    int*    row1   = (int*)(ws + OFF_R1);
    int*    rowtok = (int*)(ws + OFF_RT);
    ushort* Xp     = (ushort*)(ws + OFF_XP);
    ushort* W1T    = (ushort*)(ws + OFF_W1T);
    ushort* W2T    = (ushort*)(ws + OFF_W2T);
    ushort* H1     = (ushort*)(ws + OFF_H1);
    ushort* Y      = (ushort*)(ws + OFF_Y);

    hipMemsetAsync(ws, 0, 256, stream);                         // counts/fill/off
    hipMemsetAsync(rowtok, 0xFF, (size_t)NR_MAX * 4, stream);   // row_token = -1

    gate_kernel<<<T_TOKENS / 4, 256, 0, stream>>>(x, Wg, bg, logits, counts, e0a, e1a, w0a, w1a);
    offsets_kernel<<<1, 64, 0, stream>>>(counts, offp);
    assign_kernel<<<T_TOKENS / 256, 256, 0, stream>>>(e0a, e1a, offp, fill, row0, row1, rowtok);
    gather_kernel<<<NR_MAX, 256, 0, stream>>>(x, rowtok, Xp);
    transpose_cvt_kernel<<<dim3(FF / 64, HD / 64, NEXP), 256, 0, stream>>>(W1, W1T, HD, FF);
    transpose_cvt_kernel<<<dim3(HD / 64, FF / 64, NEXP), 256, 0, stream>>>(W2, W2T, FF, HD);
    gemm8p_kernel<HD, FF, true, 256, 2, 4>
        <<<(FF / 256) * (NR_MAX / 256), 512, 0, stream>>>(Xp, W1T, b1, H1, offp);
    gemm8p_kernel<FF, HD, false, 128, 4, 2>
        <<<(HD / 128) * (NR_MAX / 256), 512, 0, stream>>>(H1, W2T, b2, Y, offp);
    combine_kernel<<<T_TOKENS, 256, 0, stream>>>(Y, row0, row1, w0a, w1a, out);
}

// Round 3
// 892.421 us; speedup vs baseline: 1.0321x; 1.0321x over previous
//
#include <hip/hip_runtime.h>
#include <hip/hip_bf16.h>

// ---------------- problem constants ----------------
#define T_TOKENS 8192
#define HD 1024
#define FF 4096
#define NEXP 8
#define NR_MAX 18432   // 16384 picks + 8 experts * 256-row padding

typedef __attribute__((ext_vector_type(8))) short bf16x8;
typedef __attribute__((ext_vector_type(4))) float f32x4;
typedef unsigned short ushort8v __attribute__((ext_vector_type(8)));

static __device__ __forceinline__ float b2f(ushort u) {
    union { unsigned u; float f; } c; c.u = ((unsigned)u) << 16; return c.f;
}
static __device__ __forceinline__ ushort f2b(float f) {
    union { float f; unsigned u; } c; c.f = f;
    unsigned r = c.u + 0x7fffu + ((c.u >> 16) & 1u);   // RNE
    return (ushort)(r >> 16);
}

// ---------------- gate: logits, softmax, top-2, counts ----------------
__global__ __launch_bounds__(256) void gate_kernel(
    const float* __restrict__ x, const float* __restrict__ Wg, const float* __restrict__ bg,
    float* __restrict__ logits, int* __restrict__ counts,
    int* __restrict__ e0a, int* __restrict__ e1a,
    float* __restrict__ w0a, float* __restrict__ w1a)
{
    int t = blockIdx.x * 4 + (threadIdx.x >> 6);
    int l = threadIdx.x & 63;
    const float* xr = x + (size_t)t * HD;
    float acc[8] = {0,0,0,0,0,0,0,0};
    #pragma unroll
    for (int i = 0; i < 4; ++i) {
        int h0 = i * 256 + l * 4;
        float4 xv = *(const float4*)(xr + h0);
        #pragma unroll
        for (int j = 0; j < 4; ++j) {
            float xs = (&xv.x)[j];
            const float4* wr = (const float4*)(Wg + (size_t)(h0 + j) * NEXP);
            float4 wa = wr[0], wb = wr[1];
            acc[0] = fmaf(xs, wa.x, acc[0]);
            acc[1] = fmaf(xs, wa.y, acc[1]);
            acc[2] = fmaf(xs, wa.z, acc[2]);
            acc[3] = fmaf(xs, wa.w, acc[3]);
            acc[4] = fmaf(xs, wb.x, acc[4]);
            acc[5] = fmaf(xs, wb.y, acc[5]);
            acc[6] = fmaf(xs, wb.z, acc[6]);
            acc[7] = fmaf(xs, wb.w, acc[7]);
        }
    }
    #pragma unroll
    for (int off = 32; off > 0; off >>= 1) {
        #pragma unroll
        for (int e = 0; e < 8; ++e) acc[e] += __shfl_down(acc[e], off, 64);
    }
    if (l == 0) {
        float lg[8];
        #pragma unroll
        for (int e = 0; e < 8; ++e) {
            lg[e] = acc[e] + bg[e];
            logits[(size_t)t * NEXP + e] = lg[e];
        }
        float m = lg[0];
        #pragma unroll
        for (int e = 1; e < 8; ++e) m = fmaxf(m, lg[e]);
        float p[8], s = 0.f;
        #pragma unroll
        for (int e = 0; e < 8; ++e) { p[e] = expf(lg[e] - m); s += p[e]; }
        float inv = 1.f / s;
        #pragma unroll
        for (int e = 0; e < 8; ++e) p[e] *= inv;
        int i0 = 0;
        #pragma unroll
        for (int e = 1; e < 8; ++e) if (p[e] > p[i0]) i0 = e;
        int i1 = (i0 == 0) ? 1 : 0;
        #pragma unroll
        for (int e = 0; e < 8; ++e) if (e != i0 && p[e] > p[i1]) i1 = e;
        float ed = expf(p[i1] - p[i0]);          // <= 1
        float w0 = 1.f / (1.f + ed);
        float w1 = ed / (1.f + ed);
        e0a[t] = i0; e1a[t] = i1; w0a[t] = w0; w1a[t] = w1;
        atomicAdd(&counts[i0], 1);
        atomicAdd(&counts[i1], 1);
    }
}

// ---------------- offsets: pad each expert segment to 256 rows ----------------
__global__ void offsets_kernel(const int* __restrict__ counts, int* __restrict__ off) {
    if (threadIdx.x == 0) {
        int o = 0;
        for (int e = 0; e < 8; ++e) { off[e] = o; o += (counts[e] + 255) & ~255; }
        off[8] = o;
    }
}

// ---------------- assign rows ----------------
__global__ __launch_bounds__(256) void assign_kernel(
    const int* __restrict__ e0a, const int* __restrict__ e1a,
    const int* __restrict__ off, int* __restrict__ fill,
    int* __restrict__ row0, int* __restrict__ row1, int* __restrict__ row_token)
{
    int t = blockIdx.x * 256 + threadIdx.x;
    if (t >= T_TOKENS) return;
    int e0 = e0a[t];
    int r0 = off[e0] + atomicAdd(&fill[e0], 1);
    row0[t] = r0; row_token[r0] = t;
    int e1 = e1a[t];
    int r1 = off[e1] + atomicAdd(&fill[e1], 1);
    row1[t] = r1; row_token[r1] = t;
}

// ---------------- gather x rows -> bf16 X_perm (zeros in padding rows) ----------------
__global__ __launch_bounds__(256) void gather_kernel(
    const float* __restrict__ x, const int* __restrict__ row_token, ushort* __restrict__ Xp)
{
    int r = blockIdx.x;
    int tok = row_token[r];
    int c = threadIdx.x * 4;
    ushort4 o;
    if (tok >= 0 && tok < T_TOKENS) {
        float4 v = *(const float4*)(x + (size_t)tok * HD + c);
        o.x = f2b(v.x); o.y = f2b(v.y); o.z = f2b(v.z); o.w = f2b(v.w);
    } else {
        o.x = 0; o.y = 0; o.z = 0; o.w = 0;
    }
    *(ushort4*)(Xp + (size_t)r * HD + c) = o;
}

// ---------------- fp32 [R][C] -> bf16 [C][R] transpose+convert (per expert in z) ----------------
__global__ __launch_bounds__(256) void transpose_cvt_kernel(
    const float* __restrict__ in, ushort* __restrict__ out, int R, int C)
{
    __shared__ ushort tile[64][65];
    size_t esz = (size_t)R * C;
    const float* ein = in + (size_t)blockIdx.z * esz;
    ushort* eout = out + (size_t)blockIdx.z * esz;
    int c0 = blockIdx.x * 64, r0 = blockIdx.y * 64;
    int tr = threadIdx.x >> 4;            // 0..15
    int tc = (threadIdx.x & 15) * 4;      // 0..60
    #pragma unroll
    for (int i = 0; i < 4; ++i) {
        int r = tr + i * 16;
        float4 v = *(const float4*)(ein + (size_t)(r0 + r) * C + c0 + tc);
        tile[r][tc + 0] = f2b(v.x);
        tile[r][tc + 1] = f2b(v.y);
        tile[r][tc + 2] = f2b(v.z);
        tile[r][tc + 3] = f2b(v.w);
    }
    __syncthreads();
    int twc = threadIdx.x >> 3;           // 0..31 : output row (input col) within tile
    int twr = (threadIdx.x & 7) * 8;      // 0..56 : output col (input row) base
    #pragma unroll
    for (int i = 0; i < 2; ++i) {
        int cc = twc + i * 32;
        ushort8v v;
        #pragma unroll
        for (int j = 0; j < 8; ++j) v[j] = tile[twr + j][cc];
        *(ushort8v*)(eout + (size_t)(c0 + cc) * R + r0 + twr) = v;   // 16B store
    }
}

// ---------------- MFMA GEMM: ring-3, counted vmcnt, phase interleave ----------------
// C[rows x NTOT] = A[rows x K] * B^T[NTOT x K] + bias. 256xBN tile, BK=32,
// 8 waves (WM x WN). Conflict-free swizzle (round-1-proven):
//   LDS[r][s] = G[r][ s ^ ((r>>1)&3) ]  (within each 16-row group)
//   read: slot = lk ^ ((lr>>1)&3)  -> banks tiled 2x (free)
template<int K, int NTOT, bool RELU, int BN, int WM, int WN>
__global__ __launch_bounds__(512, 2) void gemm_rp_kernel(
    const ushort* __restrict__ A, const ushort* __restrict__ Bt,
    const float* __restrict__ bias, ushort* __restrict__ Out,
    const int* __restrict__ off)
{
    constexpr int BM = 256, BK = 32;
    constexpr int MREP = BM / (WM * 16);          // 8 (G1) / 4 (G2)
    constexpr int NREP = BN / (WN * 16);          // 4
    constexpr int PHASES = (MREP * NREP) / 16;    // 2 (G1) / 1 (G2)
    constexpr int MPP = MREP / PHASES;            // 4
    constexpr int A_ISS = (BM * BK) / (512 * 8);  // 2
    constexpr int B_ISS = (BN * BK) / (512 * 8);  // 2 (G1) / 1 (G2)
    constexpr int LPT = A_ISS + B_ISS;            // 4 / 3
    constexpr int KT = K / BK;
    constexpr int NT = NTOT / BN;

    __shared__ __align__(16) ushort ldsA[3][BM * BK];
    __shared__ __align__(16) ushort ldsB[3][BN * BK];

    // bijective XCD swizzle (gridDim.x is a multiple of 8)
    int nwg = gridDim.x;
    int bid = blockIdx.x;
    int wgid = (bid & 7) * (nwg >> 3) + (bid >> 3);
    int ntile = wgid % NT;
    int mtile = wgid / NT;
    int r0 = mtile * BM;
    int total = off[8];
    if (r0 >= total) return;
    int e = 0;
    #pragma unroll
    for (int q = 0; q < 7; ++q) if (r0 >= off[q + 1]) e = q + 1;

    int tid = threadIdx.x;
    int wid = tid >> 6, lane = tid & 63;
    int wr = wid / WN, wc = wid % WN;
    int lr = lane & 15, lk = lane >> 4;

    const ushort* Ab = A + (size_t)r0 * K;
    const ushort* Bb = Bt + ((size_t)e * NTOT + (size_t)ntile * BN) * K;

    int srow = tid >> 2;                          // 0..127
    int schunk = (tid & 3) ^ ((tid >> 3) & 3);    // proven conflict-free pre-swizzle

    auto stageA = [&](int kt, int sl) {
        ushort* dst = &ldsA[sl][tid * 8];
        const ushort* g = Ab + (size_t)kt * BK + (size_t)srow * K + schunk * 8;
        #pragma unroll
        for (int i = 0; i < A_ISS; ++i)
            __builtin_amdgcn_global_load_lds(
                (const __attribute__((address_space(1))) void*)(g + (size_t)i * 128 * K),
                (__attribute__((address_space(3))) void*)(dst + i * 4096),
                16, 0, 0);
    };
    auto stageB = [&](int kt, int sl) {
        ushort* dst = &ldsB[sl][tid * 8];
        const ushort* g = Bb + (size_t)kt * BK + (size_t)srow * K + schunk * 8;
        #pragma unroll
        for (int i = 0; i < B_ISS; ++i)
            __builtin_amdgcn_global_load_lds(
                (const __attribute__((address_space(1))) void*)(g + (size_t)i * 128 * K),
                (__attribute__((address_space(3))) void*)(dst + i * 4096),
                16, 0, 0);
    };
    int rchunk = lk ^ ((lr >> 1) & 3);            // conflict-free read slot
    auto ldA = [&](int sl, int m) -> bf16x8 {
        int row = wr * (BM / WM) + m * 16 + lr;
        return *(const bf16x8*)&ldsA[sl][row * 32 + rchunk * 8];
    };
    auto ldB = [&](int sl, int n) -> bf16x8 {
        int row = wc * (BN / WN) + n * 16 + lr;
        return *(const bf16x8*)&ldsB[sl][row * 32 + rchunk * 8];
    };

    f32x4 acc[MREP][NREP];
    #pragma unroll
    for (int m = 0; m < MREP; ++m)
        #pragma unroll
        for (int n = 0; n < NREP; ++n) acc[m][n] = (f32x4){0.f, 0.f, 0.f, 0.f};

    // prologue: stage tiles 0 and 1; wait tile 0 (counted — tile 1 stays in flight)
    stageA(0, 0); stageB(0, 0);
    stageA(1, 1); stageB(1, 1);
    asm volatile("s_waitcnt vmcnt(%0)" :: "n"(LPT) : "memory");
    __builtin_amdgcn_sched_barrier(0);
    __builtin_amdgcn_s_barrier();
    __builtin_amdgcn_sched_barrier(0);

    int slot = 0, snx = 2;
    for (int t = 0; t < KT; ++t) {
        // ---- phase 0: frags + stage A(t+2) ----
        bf16x8 a0[MPP], b[NREP];
        #pragma unroll
        for (int m = 0; m < MPP; ++m) a0[m] = ldA(slot, m);
        #pragma unroll
        for (int n = 0; n < NREP; ++n) b[n] = ldB(slot, n);
        if (t + 2 < KT) {
            stageA(t + 2, snx);
            if constexpr (PHASES == 1) stageB(t + 2, snx);
        }
        __builtin_amdgcn_sched_barrier(0);
        __builtin_amdgcn_s_barrier();
        asm volatile("s_waitcnt lgkmcnt(0)" ::: "memory");
        __builtin_amdgcn_sched_barrier(0);
        __builtin_amdgcn_s_setprio(1);
        #pragma unroll
        for (int m = 0; m < MPP; ++m)
            #pragma unroll
            for (int n = 0; n < NREP; ++n)
                acc[m][n] = __builtin_amdgcn_mfma_f32_16x16x32_bf16(a0[m], b[n], acc[m][n], 0, 0, 0);
        __builtin_amdgcn_sched_barrier(0);
        __builtin_amdgcn_s_setprio(0);

        if constexpr (PHASES == 2) {
            // ---- phase 1: other m-half + stage B(t+2); reuse b[] ----
            __builtin_amdgcn_s_barrier();
            bf16x8 a1[MPP];
            #pragma unroll
            for (int m = 0; m < MPP; ++m) a1[m] = ldA(slot, MPP + m);
            if (t + 2 < KT) stageB(t + 2, snx);
            __builtin_amdgcn_sched_barrier(0);
            __builtin_amdgcn_s_barrier();
            asm volatile("s_waitcnt lgkmcnt(0)" ::: "memory");
            __builtin_amdgcn_sched_barrier(0);
            __builtin_amdgcn_s_setprio(1);
            #pragma unroll
            for (int m = 0; m < MPP; ++m)
                #pragma unroll
                for (int n = 0; n < NREP; ++n)
                    acc[MPP + m][n] = __builtin_amdgcn_mfma_f32_16x16x32_bf16(a1[m], b[n], acc[MPP + m][n], 0, 0, 0);
            __builtin_amdgcn_sched_barrier(0);
            __builtin_amdgcn_s_setprio(0);
        }

        // ---- tile end: counted vmcnt (never 0 in steady state) + barrier ----
        if (t + 3 <= KT) {
            asm volatile("s_waitcnt vmcnt(%0)" :: "n"(LPT) : "memory");
        } else if (t + 2 <= KT) {
            asm volatile("s_waitcnt vmcnt(0)" ::: "memory");
        }
        if (t + 1 < KT) {
            __builtin_amdgcn_sched_barrier(0);
            __builtin_amdgcn_s_barrier();
            __builtin_amdgcn_sched_barrier(0);
        }
        slot = (slot == 2) ? 0 : slot + 1;
        snx  = (snx  == 2) ? 0 : snx  + 1;
    }

    // epilogue: bias (+ReLU) -> bf16. C/D map: col = lane&15, row = (lane>>4)*4 + j
    int c0 = ntile * BN + wc * (BN / WN);
    int rbase = r0 + wr * (BM / WM);
    #pragma unroll
    for (int ni = 0; ni < NREP; ++ni) {
        int n = c0 + ni * 16 + lr;
        float bv = bias[(size_t)e * NTOT + n];
        #pragma unroll
        for (int mi = 0; mi < MREP; ++mi) {
            int m = rbase + mi * 16 + lk * 4;
            #pragma unroll
            for (int j = 0; j < 4; ++j) {
                float v = acc[mi][ni][j] + bv;
                if (RELU) v = fmaxf(v, 0.f);
                Out[(size_t)(m + j) * NTOT + n] = f2b(v);
            }
        }
    }
}

// ---------------- combine: out[t] = w0*Y[r0] + w1*Y[r1] ----------------
__global__ __launch_bounds__(256) void combine_kernel(
    const ushort* __restrict__ Y, const int* __restrict__ row0, const int* __restrict__ row1,
    const float* __restrict__ w0a, const float* __restrict__ w1a, float* __restrict__ out)
{
    int t = blockIdx.x;
    int c = threadIdx.x * 4;
    int r0 = row0[t], r1 = row1[t];
    float w0 = w0a[t], w1 = w1a[t];
    ushort4 ya = *(const ushort4*)(Y + (size_t)r0 * HD + c);
    ushort4 yb = *(const ushort4*)(Y + (size_t)r1 * HD + c);
    float4 o;
    o.x = w0 * b2f(ya.x) + w1 * b2f(yb.x);
    o.y = w0 * b2f(ya.y) + w1 * b2f(yb.y);
    o.z = w0 * b2f(ya.z) + w1 * b2f(yb.z);
    o.w = w0 * b2f(ya.w) + w1 * b2f(yb.w);
    *(float4*)(out + (size_t)t * HD + c) = o;
}

// ---------------- workspace layout ----------------
#define WSA(x) (((x) + 255) & ~(size_t)255)
static constexpr size_t OFF_COUNTS = 0;
static constexpr size_t OFF_FILL   = 64;
static constexpr size_t OFF_OFF    = 128;
static constexpr size_t OFF_E0     = 256;
static constexpr size_t OFF_E1     = OFF_E0 + (size_t)T_TOKENS * 4;
static constexpr size_t OFF_W0     = OFF_E1 + (size_t)T_TOKENS * 4;
static constexpr size_t OFF_W1A    = OFF_W0 + (size_t)T_TOKENS * 4;
static constexpr size_t OFF_R0     = OFF_W1A + (size_t)T_TOKENS * 4;
static constexpr size_t OFF_R1     = OFF_R0 + (size_t)T_TOKENS * 4;
static constexpr size_t OFF_RT     = OFF_R1 + (size_t)T_TOKENS * 4;
static constexpr size_t OFF_XP     = WSA(OFF_RT + (size_t)NR_MAX * 4);
static constexpr size_t OFF_W1T    = OFF_XP  + (size_t)NR_MAX * HD * 2;
static constexpr size_t OFF_W2T    = OFF_W1T + (size_t)NEXP * FF * HD * 2;
static constexpr size_t OFF_H1     = OFF_W2T + (size_t)NEXP * HD * FF * 2;
static constexpr size_t OFF_Y      = OFF_H1  + (size_t)NR_MAX * FF * 2;
static constexpr size_t WS_NEEDED  = OFF_Y   + (size_t)NR_MAX * HD * 2;

extern "C" void kernel_launch(void* const* d_in, const int* in_sizes, int n_in,
                              void* d_out, int out_size, void* d_ws, size_t ws_size,
                              hipStream_t stream) {
    (void)in_sizes; (void)n_in; (void)out_size;
    const float* x  = (const float*)d_in[0];
    const float* Wg = (const float*)d_in[1];
    const float* bg = (const float*)d_in[2];
    const float* W1 = (const float*)d_in[3];
    const float* b1 = (const float*)d_in[4];
    const float* W2 = (const float*)d_in[5];
    const float* b2 = (const float*)d_in[6];
    float* out    = (float*)d_out;
    float* logits = out + (size_t)T_TOKENS * HD;

    if (ws_size < WS_NEEDED) return;  // need ~361 MB scratch

    char* ws = (char*)d_ws;
    int*    counts = (int*)(ws + OFF_COUNTS);
    int*    fill   = (int*)(ws + OFF_FILL);
    int*    offp   = (int*)(ws + OFF_OFF);
    int*    e0a    = (int*)(ws + OFF_E0);
    int*    e1a    = (int*)(ws + OFF_E1);
    float*  w0a    = (float*)(ws + OFF_W0);
    float*  w1a    = (float*)(ws + OFF_W1A);
    int*    row0   = (int*)(ws + OFF_R0);
    int*    row1   = (int*)(ws + OFF_R1);
    int*    rowtok = (int*)(ws + OFF_RT);
    ushort* Xp     = (ushort*)(ws + OFF_XP);
    ushort* W1T    = (ushort*)(ws + OFF_W1T);
    ushort* W2T    = (ushort*)(ws + OFF_W2T);
    ushort* H1     = (ushort*)(ws + OFF_H1);
    ushort* Y      = (ushort*)(ws + OFF_Y);

    hipMemsetAsync(ws, 0, 256, stream);                         // counts/fill/off
    hipMemsetAsync(rowtok, 0xFF, (size_t)NR_MAX * 4, stream);   // row_token = -1

    gate_kernel<<<T_TOKENS / 4, 256, 0, stream>>>(x, Wg, bg, logits, counts, e0a, e1a, w0a, w1a);
    offsets_kernel<<<1, 64, 0, stream>>>(counts, offp);
    assign_kernel<<<T_TOKENS / 256, 256, 0, stream>>>(e0a, e1a, offp, fill, row0, row1, rowtok);
    gather_kernel<<<NR_MAX, 256, 0, stream>>>(x, rowtok, Xp);
    transpose_cvt_kernel<<<dim3(FF / 64, HD / 64, NEXP), 256, 0, stream>>>(W1, W1T, HD, FF);
    transpose_cvt_kernel<<<dim3(HD / 64, FF / 64, NEXP), 256, 0, stream>>>(W2, W2T, FF, HD);
    gemm_rp_kernel<HD, FF, true, 256, 2, 4>
        <<<(FF / 256) * (NR_MAX / 256), 512, 0, stream>>>(Xp, W1T, b1, H1, offp);
    gemm_rp_kernel<FF, HD, false, 128, 4, 2>
        <<<(HD / 128) * (NR_MAX / 256), 512, 0, stream>>>(H1, W2T, b2, Y, offp);
    combine_kernel<<<T_TOKENS, 256, 0, stream>>>(Y, row0, row1, w0a, w1a, out);
}

// Round 4
// 780.464 us; speedup vs baseline: 1.1801x; 1.1434x over previous
//
#include <hip/hip_runtime.h>
#include <hip/hip_bf16.h>

// ---------------- problem constants ----------------
#define T_TOKENS 8192
#define HD 1024
#define FF 4096
#define NEXP 8
#define NR_MAX 17408   // 16384 picks + 8 experts * 127 max pad, rounded to 128

typedef __attribute__((ext_vector_type(8))) short bf16x8;
typedef __attribute__((ext_vector_type(4))) float f32x4;
typedef unsigned short ushort8v __attribute__((ext_vector_type(8)));

static __device__ __forceinline__ float b2f(ushort u) {
    union { unsigned u; float f; } c; c.u = ((unsigned)u) << 16; return c.f;
}
static __device__ __forceinline__ ushort f2b(float f) {
    union { float f; unsigned u; } c; c.f = f;
    unsigned r = c.u + 0x7fffu + ((c.u >> 16) & 1u);   // RNE
    return (ushort)(r >> 16);
}

// ---------------- gate: logits, softmax, top-2, counts ----------------
__global__ __launch_bounds__(256) void gate_kernel(
    const float* __restrict__ x, const float* __restrict__ Wg, const float* __restrict__ bg,
    float* __restrict__ logits, int* __restrict__ counts,
    int* __restrict__ e0a, int* __restrict__ e1a,
    float* __restrict__ w0a, float* __restrict__ w1a)
{
    int t = blockIdx.x * 4 + (threadIdx.x >> 6);
    int l = threadIdx.x & 63;
    const float* xr = x + (size_t)t * HD;
    float acc[8] = {0,0,0,0,0,0,0,0};
    #pragma unroll
    for (int i = 0; i < 4; ++i) {
        int h0 = i * 256 + l * 4;
        float4 xv = *(const float4*)(xr + h0);
        #pragma unroll
        for (int j = 0; j < 4; ++j) {
            float xs = (&xv.x)[j];
            const float4* wr = (const float4*)(Wg + (size_t)(h0 + j) * NEXP);
            float4 wa = wr[0], wb = wr[1];
            acc[0] = fmaf(xs, wa.x, acc[0]);
            acc[1] = fmaf(xs, wa.y, acc[1]);
            acc[2] = fmaf(xs, wa.z, acc[2]);
            acc[3] = fmaf(xs, wa.w, acc[3]);
            acc[4] = fmaf(xs, wb.x, acc[4]);
            acc[5] = fmaf(xs, wb.y, acc[5]);
            acc[6] = fmaf(xs, wb.z, acc[6]);
            acc[7] = fmaf(xs, wb.w, acc[7]);
        }
    }
    #pragma unroll
    for (int off = 32; off > 0; off >>= 1) {
        #pragma unroll
        for (int e = 0; e < 8; ++e) acc[e] += __shfl_down(acc[e], off, 64);
    }
    if (l == 0) {
        float lg[8];
        #pragma unroll
        for (int e = 0; e < 8; ++e) {
            lg[e] = acc[e] + bg[e];
            logits[(size_t)t * NEXP + e] = lg[e];
        }
        float m = lg[0];
        #pragma unroll
        for (int e = 1; e < 8; ++e) m = fmaxf(m, lg[e]);
        float p[8], s = 0.f;
        #pragma unroll
        for (int e = 0; e < 8; ++e) { p[e] = expf(lg[e] - m); s += p[e]; }
        float inv = 1.f / s;
        #pragma unroll
        for (int e = 0; e < 8; ++e) p[e] *= inv;
        int i0 = 0;
        #pragma unroll
        for (int e = 1; e < 8; ++e) if (p[e] > p[i0]) i0 = e;
        int i1 = (i0 == 0) ? 1 : 0;
        #pragma unroll
        for (int e = 0; e < 8; ++e) if (e != i0 && p[e] > p[i1]) i1 = e;
        float ed = expf(p[i1] - p[i0]);          // <= 1
        float w0 = 1.f / (1.f + ed);
        float w1 = ed / (1.f + ed);
        e0a[t] = i0; e1a[t] = i1; w0a[t] = w0; w1a[t] = w1;
        atomicAdd(&counts[i0], 1);
        atomicAdd(&counts[i1], 1);
    }
}

// ---------------- offsets: pad each expert segment to 128 rows ----------------
__global__ void offsets_kernel(const int* __restrict__ counts, int* __restrict__ off) {
    if (threadIdx.x == 0) {
        int o = 0;
        for (int e = 0; e < 8; ++e) { off[e] = o; o += (counts[e] + 127) & ~127; }
        off[8] = o;
    }
}

// ---------------- assign rows ----------------
__global__ __launch_bounds__(256) void assign_kernel(
    const int* __restrict__ e0a, const int* __restrict__ e1a,
    const int* __restrict__ off, int* __restrict__ fill,
    int* __restrict__ row0, int* __restrict__ row1, int* __restrict__ row_token)
{
    int t = blockIdx.x * 256 + threadIdx.x;
    if (t >= T_TOKENS) return;
    int e0 = e0a[t];
    int r0 = off[e0] + atomicAdd(&fill[e0], 1);
    row0[t] = r0; row_token[r0] = t;
    int e1 = e1a[t];
    int r1 = off[e1] + atomicAdd(&fill[e1], 1);
    row1[t] = r1; row_token[r1] = t;
}

// ---------------- gather x rows -> bf16 X_perm (zeros in padding rows) ----------------
__global__ __launch_bounds__(256) void gather_kernel(
    const float* __restrict__ x, const int* __restrict__ row_token, ushort* __restrict__ Xp)
{
    int r = blockIdx.x;
    int tok = row_token[r];
    int c = threadIdx.x * 4;
    ushort4 o;
    if (tok >= 0 && tok < T_TOKENS) {
        float4 v = *(const float4*)(x + (size_t)tok * HD + c);
        o.x = f2b(v.x); o.y = f2b(v.y); o.z = f2b(v.z); o.w = f2b(v.w);
    } else {
        o.x = 0; o.y = 0; o.z = 0; o.w = 0;
    }
    *(ushort4*)(Xp + (size_t)r * HD + c) = o;
}

// ---------------- fp32 [R][C] -> bf16 [C][R] transpose+convert (per expert in z) ----------------
__global__ __launch_bounds__(256) void transpose_cvt_kernel(
    const float* __restrict__ in, ushort* __restrict__ out, int R, int C)
{
    __shared__ ushort tile[64][65];
    size_t esz = (size_t)R * C;
    const float* ein = in + (size_t)blockIdx.z * esz;
    ushort* eout = out + (size_t)blockIdx.z * esz;
    int c0 = blockIdx.x * 64, r0 = blockIdx.y * 64;
    int tr = threadIdx.x >> 4;            // 0..15
    int tc = (threadIdx.x & 15) * 4;      // 0..60
    #pragma unroll
    for (int i = 0; i < 4; ++i) {
        int r = tr + i * 16;
        float4 v = *(const float4*)(ein + (size_t)(r0 + r) * C + c0 + tc);
        tile[r][tc + 0] = f2b(v.x);
        tile[r][tc + 1] = f2b(v.y);
        tile[r][tc + 2] = f2b(v.z);
        tile[r][tc + 3] = f2b(v.w);
    }
    __syncthreads();
    int twc = threadIdx.x >> 3;           // 0..31 : output row (input col) within tile
    int twr = (threadIdx.x & 7) * 8;      // 0..56 : output col (input row) base
    #pragma unroll
    for (int i = 0; i < 2; ++i) {
        int cc = twc + i * 32;
        ushort8v v;
        #pragma unroll
        for (int j = 0; j < 8; ++j) v[j] = tile[twr + j][cc];
        *(ushort8v*)(eout + (size_t)(c0 + cc) * R + r0 + twr) = v;   // 16B store
    }
}

// ---------------- MFMA GEMM (round-1-proven structure + XCD swizzle) ----------------
// C[rows x NTOT] = A[rows x K] * B^T[NTOT x K] + bias, 128x128 tile, BK=32,
// 4 waves (2x2 of 64x64), mfma_f32_16x16x32_bf16, compiler-scheduled 2-barrier
// dbuf loop, global_load_lds width 16 with pre-swizzled source (0 bank conflicts).
template<int K, int NTOT, bool RELU>
__global__ __launch_bounds__(256) void gemm_kernel(
    const ushort* __restrict__ A, const ushort* __restrict__ Bt,
    const float* __restrict__ bias, ushort* __restrict__ Out,
    const int* __restrict__ off)
{
    constexpr int NT = NTOT / 128;
    __shared__ __align__(16) ushort lds[2][2][128 * 32];

    // bijective XCD swizzle (gridDim.x % 8 == 0); n-fastest within each chunk
    int nwg = gridDim.x;
    int bid = blockIdx.x;
    int wgid = (bid & 7) * (nwg >> 3) + (bid >> 3);
    int ntile = wgid % NT;
    int mtile = wgid / NT;
    int r0 = mtile * 128;
    int total = off[8];
    if (r0 >= total) return;
    int e = 0;
    #pragma unroll
    for (int q = 0; q < 7; ++q) if (r0 >= off[q + 1]) e = q + 1;

    int tid = threadIdx.x;
    int w = tid >> 6, lane = tid & 63;
    int wr = w >> 1, wc = w & 1;
    int lr = lane & 15, lk = lane >> 4;

    const ushort* Ab = A + (size_t)r0 * K;
    const ushort* Bb = Bt + ((size_t)e * NTOT + (size_t)ntile * 128) * K;

    auto stage = [&](const ushort* gbase, ushort* ldsbase) {
        #pragma unroll
        for (int issue = 0; issue < 2; ++issue) {
            int row = issue * 64 + w * 16 + (lane >> 2);
            int chunk = (lane & 3) ^ ((lane >> 3) & 3);   // pre-swizzle source
            const ushort* g = gbase + (size_t)row * K + chunk * 8;
            ushort* lp = ldsbase + (issue * 64 + w * 16) * 32;
            __builtin_amdgcn_global_load_lds(
                (const __attribute__((address_space(1))) void*)g,
                (__attribute__((address_space(3))) void*)lp, 16, 0, 0);
        }
    };

    stage(Ab, &lds[0][0][0]);
    stage(Bb, &lds[0][1][0]);

    f32x4 acc[4][4];
    #pragma unroll
    for (int mi = 0; mi < 4; ++mi)
        #pragma unroll
        for (int ni = 0; ni < 4; ++ni) acc[mi][ni] = (f32x4){0.f, 0.f, 0.f, 0.f};

    __syncthreads();

    constexpr int KT = K / 32;
    int cur = 0;
    int slot = lk ^ ((lr >> 1) & 3);                      // swizzled read slot
    for (int kt = 0; kt < KT; ++kt) {
        if (kt + 1 < KT) {
            stage(Ab + (kt + 1) * 32, &lds[cur ^ 1][0][0]);
            stage(Bb + (kt + 1) * 32, &lds[cur ^ 1][1][0]);
        }
        const ushort* As = &lds[cur][0][0];
        const ushort* Bs = &lds[cur][1][0];
        bf16x8 a[4], b[4];
        #pragma unroll
        for (int mi = 0; mi < 4; ++mi)
            a[mi] = *(const bf16x8*)(As + (wr * 64 + mi * 16 + lr) * 32 + slot * 8);
        #pragma unroll
        for (int ni = 0; ni < 4; ++ni)
            b[ni] = *(const bf16x8*)(Bs + (wc * 64 + ni * 16 + lr) * 32 + slot * 8);
        #pragma unroll
        for (int mi = 0; mi < 4; ++mi)
            #pragma unroll
            for (int ni = 0; ni < 4; ++ni)
                acc[mi][ni] = __builtin_amdgcn_mfma_f32_16x16x32_bf16(
                    a[mi], b[ni], acc[mi][ni], 0, 0, 0);
        __syncthreads();
        cur ^= 1;
    }

    // epilogue: bias (+ReLU) -> bf16 store. C/D map: col = lane&15, row = (lane>>4)*4 + j
    int c0 = ntile * 128 + wc * 64;
    int rbase = r0 + wr * 64;
    #pragma unroll
    for (int ni = 0; ni < 4; ++ni) {
        int n = c0 + ni * 16 + lr;
        float bv = bias[(size_t)e * NTOT + n];
        #pragma unroll
        for (int mi = 0; mi < 4; ++mi) {
            int m = rbase + mi * 16 + lk * 4;
            #pragma unroll
            for (int j = 0; j < 4; ++j) {
                float v = acc[mi][ni][j] + bv;
                if (RELU) v = fmaxf(v, 0.f);
                Out[(size_t)(m + j) * NTOT + n] = f2b(v);
            }
        }
    }
}

// ---------------- combine: out[t] = w0*Y[r0] + w1*Y[r1] ----------------
__global__ __launch_bounds__(256) void combine_kernel(
    const ushort* __restrict__ Y, const int* __restrict__ row0, const int* __restrict__ row1,
    const float* __restrict__ w0a, const float* __restrict__ w1a, float* __restrict__ out)
{
    int t = blockIdx.x;
    int c = threadIdx.x * 4;
    int r0 = row0[t], r1 = row1[t];
    float w0 = w0a[t], w1 = w1a[t];
    ushort4 ya = *(const ushort4*)(Y + (size_t)r0 * HD + c);
    ushort4 yb = *(const ushort4*)(Y + (size_t)r1 * HD + c);
    float4 o;
    o.x = w0 * b2f(ya.x) + w1 * b2f(yb.x);
    o.y = w0 * b2f(ya.y) + w1 * b2f(yb.y);
    o.z = w0 * b2f(ya.z) + w1 * b2f(yb.z);
    o.w = w0 * b2f(ya.w) + w1 * b2f(yb.w);
    *(float4*)(out + (size_t)t * HD + c) = o;
}

// ---------------- workspace layout ----------------
#define WSA(x) (((x) + 255) & ~(size_t)255)
static constexpr size_t OFF_COUNTS = 0;
static constexpr size_t OFF_FILL   = 64;
static constexpr size_t OFF_OFF    = 128;
static constexpr size_t OFF_E0     = 256;
static constexpr size_t OFF_E1     = OFF_E0 + (size_t)T_TOKENS * 4;
static constexpr size_t OFF_W0     = OFF_E1 + (size_t)T_TOKENS * 4;
static constexpr size_t OFF_W1A    = OFF_W0 + (size_t)T_TOKENS * 4;
static constexpr size_t OFF_R0     = OFF_W1A + (size_t)T_TOKENS * 4;
static constexpr size_t OFF_R1     = OFF_R0 + (size_t)T_TOKENS * 4;
static constexpr size_t OFF_RT     = OFF_R1 + (size_t)T_TOKENS * 4;
static constexpr size_t OFF_XP     = WSA(OFF_RT + (size_t)NR_MAX * 4);
static constexpr size_t OFF_W1T    = OFF_XP  + (size_t)NR_MAX * HD * 2;
static constexpr size_t OFF_W2T    = OFF_W1T + (size_t)NEXP * FF * HD * 2;
static constexpr size_t OFF_H1     = OFF_W2T + (size_t)NEXP * HD * FF * 2;
static constexpr size_t OFF_Y      = OFF_H1  + (size_t)NR_MAX * FF * 2;
static constexpr size_t WS_NEEDED  = OFF_Y   + (size_t)NR_MAX * HD * 2;

extern "C" void kernel_launch(void* const* d_in, const int* in_sizes, int n_in,
                              void* d_out, int out_size, void* d_ws, size_t ws_size,
                              hipStream_t stream) {
    (void)in_sizes; (void)n_in; (void)out_size;
    const float* x  = (const float*)d_in[0];
    const float* Wg = (const float*)d_in[1];
    const float* bg = (const float*)d_in[2];
    const float* W1 = (const float*)d_in[3];
    const float* b1 = (const float*)d_in[4];
    const float* W2 = (const float*)d_in[5];
    const float* b2 = (const float*)d_in[6];
    float* out    = (float*)d_out;
    float* logits = out + (size_t)T_TOKENS * HD;

    if (ws_size < WS_NEEDED) return;  // need ~349 MB scratch

    char* ws = (char*)d_ws;
    int*    counts = (int*)(ws + OFF_COUNTS);
    int*    fill   = (int*)(ws + OFF_FILL);
    int*    offp   = (int*)(ws + OFF_OFF);
    int*    e0a    = (int*)(ws + OFF_E0);
    int*    e1a    = (int*)(ws + OFF_E1);
    float*  w0a    = (float*)(ws + OFF_W0);
    float*  w1a    = (float*)(ws + OFF_W1A);
    int*    row0   = (int*)(ws + OFF_R0);
    int*    row1   = (int*)(ws + OFF_R1);
    int*    rowtok = (int*)(ws + OFF_RT);
    ushort* Xp     = (ushort*)(ws + OFF_XP);
    ushort* W1T    = (ushort*)(ws + OFF_W1T);
    ushort* W2T    = (ushort*)(ws + OFF_W2T);
    ushort* H1     = (ushort*)(ws + OFF_H1);
    ushort* Y      = (ushort*)(ws + OFF_Y);

    hipMemsetAsync(ws, 0, 256, stream);                         // counts/fill/off
    hipMemsetAsync(rowtok, 0xFF, (size_t)NR_MAX * 4, stream);   // row_token = -1

    gate_kernel<<<T_TOKENS / 4, 256, 0, stream>>>(x, Wg, bg, logits, counts, e0a, e1a, w0a, w1a);
    offsets_kernel<<<1, 64, 0, stream>>>(counts, offp);
    assign_kernel<<<T_TOKENS / 256, 256, 0, stream>>>(e0a, e1a, offp, fill, row0, row1, rowtok);
    gather_kernel<<<NR_MAX, 256, 0, stream>>>(x, rowtok, Xp);
    transpose_cvt_kernel<<<dim3(FF / 64, HD / 64, NEXP), 256, 0, stream>>>(W1, W1T, HD, FF);
    transpose_cvt_kernel<<<dim3(HD / 64, FF / 64, NEXP), 256, 0, stream>>>(W2, W2T, FF, HD);
    gemm_kernel<HD, FF, true>
        <<<(FF / 128) * (NR_MAX / 128), 256, 0, stream>>>(Xp, W1T, b1, H1, offp);
    gemm_kernel<FF, HD, false>
        <<<(HD / 128) * (NR_MAX / 128), 256, 0, stream>>>(H1, W2T, b2, Y, offp);
    combine_kernel<<<T_TOKENS, 256, 0, stream>>>(Y, row0, row1, w0a, w1a, out);
}